// Round 3
// baseline (263.943 us; speedup 1.0000x reference)
//
#include <hip/hip_runtime.h>

// MoE: M=4096, K=1024, E=8, N=1024, TOPK=2
// out[m] = sum_t topk_w[m,t] * ( silu(hs[m]@w1[e][:, :N]) * (hs[m]@w1[e][:, N:]) ) @ w2[e]

#define M_TOK   4096
#define K_DIM   1024
#define N_DIM   1024
#define E_NUM   8
#define NPAIR   8192            // M_TOK * TOPK
#define BM      128
#define ROWS_CAP 9216           // NPAIR + E_NUM*BM
#define NROWBLK 72              // ROWS_CAP / BM  (divisible by 8 -> bijective XCD swizzle)
#define HBLK    32              // routing blocks (NPAIR / 256)

typedef unsigned short u16;
typedef unsigned int   u32;
typedef __attribute__((ext_vector_type(8))) short bf16x8;
typedef __attribute__((ext_vector_type(4))) float f32x4;

#define GPTR(p) ((const __attribute__((address_space(1))) u32*)(const void*)(p))
#define LPTR(p) ((__attribute__((address_space(3))) u32*)(void*)(p))
#define MFMA_BF16 __builtin_amdgcn_mfma_f32_16x16x32_bf16

__device__ __forceinline__ u16 f2bf(float f) {
  union { float f; u32 u; } v; v.f = f;
  u32 r = v.u + 0x7FFFu + ((v.u >> 16) & 1u);   // RNE
  return (u16)(r >> 16);
}
__device__ __forceinline__ float bf2f(u16 u) {
  union { u32 u; float f; } v; v.u = ((u32)u) << 16;
  return v.f;
}

// ---------------- routing stage 1: per-block expert histogram (no atomics) ----
__global__ __launch_bounds__(256) void hist_kernel(
    const int* __restrict__ topk_ids, int* __restrict__ blockhist) {
  __shared__ int wcnt[4][E_NUM];
  const int t = threadIdx.x, wave = t >> 6, lane = t & 63;
  int e = topk_ids[blockIdx.x * 256 + t] & 7;
#pragma unroll
  for (int ee = 0; ee < E_NUM; ++ee) {
    unsigned long long m = __ballot(e == ee);
    if (lane == ee) wcnt[wave][ee] = (int)__popcll(m);
  }
  __syncthreads();
  if (t < E_NUM) {
    int s = wcnt[0][t] + wcnt[1][t] + wcnt[2][t] + wcnt[3][t];
    blockhist[blockIdx.x * E_NUM + t] = s;
  }
}

// ---------------- routing stage 2: scan, offsets, block_expert, pad fill ------
__global__ __launch_bounds__(256) void scan_kernel(
    const int* __restrict__ blockhist, int* __restrict__ baseoff,
    int* __restrict__ pair_token, int* __restrict__ block_expert) {
  __shared__ int cnt[E_NUM], off[E_NUM], pad[E_NUM];
  const int t = threadIdx.x;
  if (t < E_NUM) {
    int run = 0;
    for (int b = 0; b < HBLK; ++b) {
      baseoff[b * E_NUM + t] = run;          // exclusive prefix within expert t
      run += blockhist[b * E_NUM + t];
    }
    cnt[t] = run;
  }
  __syncthreads();
  if (t == 0) {
    int run = 0, blk = 0;
    for (int e = 0; e < E_NUM; ++e) {
      off[e] = run;
      int padded = ((cnt[e] + BM - 1) / BM) * BM;
      pad[e] = padded;
      for (int b = 0; b < padded / BM; ++b) block_expert[blk++] = e;
      run += padded;
    }
    for (; blk < NROWBLK; ++blk) block_expert[blk] = -1;
  }
  __syncthreads();
  // shift per-block bases by expert segment start
  for (int i = t; i < HBLK * E_NUM; i += 256) baseoff[i] += off[i & 7];
  // pad rows point at token 0 (computed, never gathered)
  for (int e = 0; e < E_NUM; ++e) {
    int s = off[e] + cnt[e], epos = off[e] + pad[e];
    for (int r = s + t; r < epos; r += 256) pair_token[r] = 0;
  }
}

// ---------------- routing stage 3: deterministic position assignment ----------
__global__ __launch_bounds__(256) void assign_kernel(
    const int* __restrict__ topk_ids, const int* __restrict__ baseoff,
    int* __restrict__ pair_token, int* __restrict__ pos_of) {
  __shared__ int wcnt[4][E_NUM], wbase[4][E_NUM];
  const int t = threadIdx.x, wave = t >> 6, lane = t & 63;
  const int p = blockIdx.x * 256 + t;
  const int e = topk_ids[p] & 7;
  int rank = 0;
#pragma unroll
  for (int ee = 0; ee < E_NUM; ++ee) {
    unsigned long long m = __ballot(e == ee);
    if (e == ee) rank = (int)__popcll(m & ((1ull << lane) - 1ull));
    if (lane == ee) wcnt[wave][ee] = (int)__popcll(m);
  }
  __syncthreads();
  if (t < E_NUM) {
    int run = baseoff[blockIdx.x * E_NUM + t];
    for (int w = 0; w < 4; ++w) { wbase[w][t] = run; run += wcnt[w][t]; }
  }
  __syncthreads();
  int pos = wbase[wave][e] + rank;
  pair_token[pos] = p >> 1;
  pos_of[p] = pos;
}

// ---------------- fp32 -> bf16 flat convert (hidden states) -------------------
__global__ __launch_bounds__(256) void convert_kernel(
    const float* __restrict__ in, u16* __restrict__ out) {
  int i = blockIdx.x * 256 + threadIdx.x;
  float4 v = ((const float4*)in)[i];
  ushort4 o;
  o.x = f2bf(v.x); o.y = f2bf(v.y); o.z = f2bf(v.z); o.w = f2bf(v.w);
  ((ushort4*)out)[i] = o;
}

// ---------------- fp32 (R,Cc) -> bf16 (Cc,R) transpose per matrix -------------
__global__ __launch_bounds__(256) void transpose_convert(
    const float* __restrict__ in, u16* __restrict__ out, int R, int Cc) {
  __shared__ float lds[64][65];
  const float* src = in + (size_t)blockIdx.z * R * Cc;
  u16* dst = out + (size_t)blockIdx.z * R * Cc;
  int r0 = blockIdx.x * 64, c0 = blockIdx.y * 64;
  int t = threadIdx.x;
#pragma unroll
  for (int it = 0; it < 16; ++it) {
    int lin = it * 256 + t;
    int rr = lin >> 6, cc = lin & 63;
    lds[cc][rr] = src[(size_t)(r0 + rr) * Cc + c0 + cc];
  }
  __syncthreads();
#pragma unroll
  for (int it = 0; it < 8; ++it) {
    int lin = it * 512 + t * 2;
    int cc = lin >> 6, rr = lin & 63;
    ushort2 o;
    o.x = f2bf(lds[cc][rr]);
    o.y = f2bf(lds[cc][rr + 1]);
    *(ushort2*)&dst[(size_t)(c0 + cc) * R + r0 + rr] = o;
  }
}

// ---------------- grouped GEMM, 128x128(xNB) tile, 8-phase counted-vmcnt ------
// NB=2: fused gate|up GEMM1 -> h = silu(gate)*up.  NB=1: plain GEMM2 -> y.
// 8 waves (2M x 4C), per-wave 64 rows x 32 cols x NB. acc[NB][4][2].
// T3+T4: raw s_barrier phases (4/tile), loads stay in flight ACROSS barriers;
// boundary waits are COUNTED (vmcnt(6) steady-state for NB=2 triple-buffer
// depth-2; vmcnt(0)-after-full-tile-cover for NB=1 double-buffer depth-1).
// T5 setprio(1) around each MFMA cluster (8-phase regime -> pays, m218b).
// Rule #18: lgkmcnt(0) asm is followed by sched_barrier(0) before MFMAs.
// XCD chunk swizzle (T1): 72 % 8 == 0 -> bx = (b&7)*9 + (b>>3) bijective.
template <bool GATHER, int NB>
__global__ __launch_bounds__(512, NB == 2 ? 1 : 4) void gemm8p(
    const u16* __restrict__ A, const u16* __restrict__ Bt, u16* __restrict__ Out,
    const int* __restrict__ pair_token, const int* __restrict__ block_expert) {
  constexpr int NBUF = (NB == 2) ? 3 : 2;
  constexpr int A_ELEMS = 128 * 64;
  constexpr int B_ELEMS = NB * 128 * 64;
  constexpr int KT = K_DIM / 64;           // 16 K-tiles
  constexpr int DEPTH = (NB == 2) ? 2 : 1; // prefetch distance

  const int bx = ((int)blockIdx.x & 7) * (NROWBLK / 8) + ((int)blockIdx.x >> 3);
  const int e = block_expert[bx];
  if (e < 0) return;
  const int by = blockIdx.y;

  extern __shared__ __align__(16) u16 smem[];
  u16* As = smem;                          // NBUF * A_ELEMS
  u16* Bs = smem + NBUF * A_ELEMS;         // NBUF * B_ELEMS

  const int tid = threadIdx.x;
  const int wave = tid >> 6;
  const int lane = tid & 63;
  const int wr  = wave >> 2;               // 0..1 row half (64 rows)
  const int wcc = wave & 3;                // 0..3 col group (32 cols)
  const int sr8 = lane >> 3;               // staging row within 8-row group
  const int kc  = ((lane & 7) ^ sr8) << 3; // pre-swizzled global chunk (elems)

  // staging pointers: per gload_lds shot, 8 waves x 8 rows = 64 rows
  const u16* apg[2];
#pragma unroll
  for (int is = 0; is < 2; ++is) {
    int rt = is * 64 + wave * 8 + sr8;
    int grow = bx * BM + rt;
    int arow = GATHER ? pair_token[grow] : grow;
    apg[is] = A + (size_t)arow * K_DIM + kc;
  }
  const u16* bpg[NB * 2];
  const u16* base_e = Bt + (size_t)e * (NB * N_DIM) * K_DIM;
#pragma unroll
  for (int is = 0; is < NB * 2; ++is) {
    int rt = is * 64 + wave * 8 + sr8;
    int nb = rt >> 7;                      // 0: gate rows, 1: up rows (NB=2)
    int n = nb * N_DIM + by * 128 + (rt & 127);
    bpg[is] = base_e + (size_t)n * K_DIM + kc;
  }

#define STAGE_A(buf, is, koff) __builtin_amdgcn_global_load_lds( \
    GPTR(apg[is] + (koff)), LPTR(&As[(buf) * A_ELEMS + (is) * 4096 + wave * 512]), 16, 0, 0)
#define STAGE_B(buf, is, koff) __builtin_amdgcn_global_load_lds( \
    GPTR(bpg[is] + (koff)), LPTR(&Bs[(buf) * B_ELEMS + (is) * 4096 + wave * 512]), 16, 0, 0)
#define RDA(dst, base, i, ks) do { const int row_ = wr * 64 + (i) * 16 + (lane & 15); \
    dst = *(const bf16x8*)&(base)[row_ * 64 + ((((ks) * 4 + (lane >> 4)) ^ (row_ & 7)) << 3)]; } while (0)
#define RDB(dst, base, nbv, j, ks) do { const int n_ = (nbv) * 128 + wcc * 32 + (j) * 16 + (lane & 15); \
    dst = *(const bf16x8*)&(base)[n_ * 64 + ((((ks) * 4 + (lane >> 4)) ^ (n_ & 7)) << 3)]; } while (0)
#define PHASE_OPEN() do { __builtin_amdgcn_s_barrier(); \
    asm volatile("s_waitcnt lgkmcnt(0)" ::: "memory"); \
    __builtin_amdgcn_sched_barrier(0); \
    __builtin_amdgcn_s_setprio(1); } while (0)
#define PHASE_CLOSE() do { __builtin_amdgcn_s_setprio(0); \
    __builtin_amdgcn_s_barrier(); } while (0)

  f32x4 acc[NB][4][2];
#pragma unroll
  for (int nb = 0; nb < NB; ++nb)
#pragma unroll
    for (int i = 0; i < 4; ++i)
#pragma unroll
      for (int j = 0; j < 2; ++j) acc[nb][i][j] = f32x4{0.f, 0.f, 0.f, 0.f};

  // ---- prologue: stage DEPTH tiles ----
  if constexpr (NB == 2) {
    STAGE_A(0, 0, 0); STAGE_A(0, 1, 0);
    STAGE_B(0, 0, 0); STAGE_B(0, 1, 0); STAGE_B(0, 2, 0); STAGE_B(0, 3, 0);
    __builtin_amdgcn_sched_barrier(0);     // keep buf0/buf1 issue groups ordered
    STAGE_A(1, 0, 64); STAGE_A(1, 1, 64);
    STAGE_B(1, 0, 64); STAGE_B(1, 1, 64); STAGE_B(1, 2, 64); STAGE_B(1, 3, 64);
    __builtin_amdgcn_sched_barrier(0);
    asm volatile("s_waitcnt vmcnt(6)" ::: "memory");   // tile0 landed; tile1 in flight
  } else {
    STAGE_A(0, 0, 0); STAGE_A(0, 1, 0);
    STAGE_B(0, 0, 0); STAGE_B(0, 1, 0);
    asm volatile("s_waitcnt vmcnt(0)" ::: "memory");   // tile0 landed
  }
  __builtin_amdgcn_s_barrier();

  int cur = 0;
  int nxt = DEPTH;                          // buffer receiving tile t+DEPTH
  for (int t = 0; t < KT; ++t) {
    const u16* Ab = &As[cur * A_ELEMS];
    const u16* Bb = &Bs[cur * B_ELEMS];
    const int koff = (t + DEPTH) * 64;
    const bool issue = (t < KT - DEPTH);

    if constexpr (NB == 2) {
      bf16x8 bq[2][2];
      // ---- phase 0: ks=0, rows 0..1 ----
      {
        bf16x8 af0, af1;
        RDA(af0, Ab, 0, 0); RDA(af1, Ab, 1, 0);
        RDB(bq[0][0], Bb, 0, 0, 0); RDB(bq[0][1], Bb, 0, 1, 0);
        RDB(bq[1][0], Bb, 1, 0, 0); RDB(bq[1][1], Bb, 1, 1, 0);
        if (issue) { STAGE_B(nxt, 0, koff); STAGE_B(nxt, 1, koff); }
        PHASE_OPEN();
#pragma unroll
        for (int nb = 0; nb < 2; ++nb)
#pragma unroll
          for (int j = 0; j < 2; ++j) {
            acc[nb][0][j] = MFMA_BF16(af0, bq[nb][j], acc[nb][0][j], 0, 0, 0);
            acc[nb][1][j] = MFMA_BF16(af1, bq[nb][j], acc[nb][1][j], 0, 0, 0);
          }
        PHASE_CLOSE();
      }
      // ---- phase 1: ks=0, rows 2..3 ----
      {
        bf16x8 af2, af3;
        RDA(af2, Ab, 2, 0); RDA(af3, Ab, 3, 0);
        if (issue) { STAGE_B(nxt, 2, koff); STAGE_B(nxt, 3, koff); }
        PHASE_OPEN();
#pragma unroll
        for (int nb = 0; nb < 2; ++nb)
#pragma unroll
          for (int j = 0; j < 2; ++j) {
            acc[nb][2][j] = MFMA_BF16(af2, bq[nb][j], acc[nb][2][j], 0, 0, 0);
            acc[nb][3][j] = MFMA_BF16(af3, bq[nb][j], acc[nb][3][j], 0, 0, 0);
          }
        PHASE_CLOSE();
      }
      // ---- phase 2: ks=1, rows 0..1 ----
      {
        bf16x8 af0, af1;
        RDA(af0, Ab, 0, 1); RDA(af1, Ab, 1, 1);
        RDB(bq[0][0], Bb, 0, 0, 1); RDB(bq[0][1], Bb, 0, 1, 1);
        RDB(bq[1][0], Bb, 1, 0, 1); RDB(bq[1][1], Bb, 1, 1, 1);
        if (issue) STAGE_A(nxt, 0, koff);
        PHASE_OPEN();
#pragma unroll
        for (int nb = 0; nb < 2; ++nb)
#pragma unroll
          for (int j = 0; j < 2; ++j) {
            acc[nb][0][j] = MFMA_BF16(af0, bq[nb][j], acc[nb][0][j], 0, 0, 0);
            acc[nb][1][j] = MFMA_BF16(af1, bq[nb][j], acc[nb][1][j], 0, 0, 0);
          }
        PHASE_CLOSE();
      }
      // ---- phase 3: ks=1, rows 2..3, then counted tile-boundary wait ----
      {
        bf16x8 af2, af3;
        RDA(af2, Ab, 2, 1); RDA(af3, Ab, 3, 1);
        if (issue) STAGE_A(nxt, 1, koff);
        PHASE_OPEN();
#pragma unroll
        for (int nb = 0; nb < 2; ++nb)
#pragma unroll
          for (int j = 0; j < 2; ++j) {
            acc[nb][2][j] = MFMA_BF16(af2, bq[nb][j], acc[nb][2][j], 0, 0, 0);
            acc[nb][3][j] = MFMA_BF16(af3, bq[nb][j], acc[nb][3][j], 0, 0, 0);
          }
        __builtin_amdgcn_s_setprio(0);
        if (t < KT - 2)       asm volatile("s_waitcnt vmcnt(6)" ::: "memory");
        else if (t == KT - 2) asm volatile("s_waitcnt vmcnt(0)" ::: "memory");
        __builtin_amdgcn_s_barrier();
      }
    } else {
      // ---- phase 0: ks=0 ----
      {
        bf16x8 af[4], bq[2];
        RDA(af[0], Ab, 0, 0); RDA(af[1], Ab, 1, 0); RDA(af[2], Ab, 2, 0); RDA(af[3], Ab, 3, 0);
        RDB(bq[0], Bb, 0, 0, 0); RDB(bq[1], Bb, 0, 1, 0);
        if (issue) { STAGE_B(nxt, 0, koff); STAGE_A(nxt, 0, koff); }
        PHASE_OPEN();
#pragma unroll
        for (int i = 0; i < 4; ++i)
#pragma unroll
          for (int j = 0; j < 2; ++j)
            acc[0][i][j] = MFMA_BF16(af[i], bq[j], acc[0][i][j], 0, 0, 0);
        PHASE_CLOSE();
      }
      // ---- phase 1: ks=1, then tile-boundary wait ----
      {
        bf16x8 af[4], bq[2];
        RDA(af[0], Ab, 0, 1); RDA(af[1], Ab, 1, 1); RDA(af[2], Ab, 2, 1); RDA(af[3], Ab, 3, 1);
        RDB(bq[0], Bb, 0, 0, 1); RDB(bq[1], Bb, 0, 1, 1);
        if (issue) { STAGE_B(nxt, 1, koff); STAGE_A(nxt, 1, koff); }
        PHASE_OPEN();
#pragma unroll
        for (int i = 0; i < 4; ++i)
#pragma unroll
          for (int j = 0; j < 2; ++j)
            acc[0][i][j] = MFMA_BF16(af[i], bq[j], acc[0][i][j], 0, 0, 0);
        __builtin_amdgcn_s_setprio(0);
        if (t < KT - 1) asm volatile("s_waitcnt vmcnt(0)" ::: "memory");
        __builtin_amdgcn_s_barrier();
      }
    }
    cur = (cur == NBUF - 1) ? 0 : cur + 1;
    nxt = (nxt == NBUF - 1) ? 0 : nxt + 1;
  }

  // epilogue: C/D layout col=lane&15, row=(lane>>4)*4+reg (m89/m91-verified)
  const size_t rbase = (size_t)bx * BM + wr * 64 + ((lane >> 4) * 4);
  const int cbase = by * 128 + wcc * 32 + (lane & 15);
#pragma unroll
  for (int i = 0; i < 4; ++i)
#pragma unroll
    for (int j = 0; j < 2; ++j)
#pragma unroll
      for (int r = 0; r < 4; ++r) {
        float v;
        if (NB == 2) {
          float g = acc[0][i][j][r], u = acc[1][i][j][r];
          v = g * u / (1.f + __expf(-g));
        } else {
          v = acc[0][i][j][r];
        }
        Out[(rbase + i * 16 + r) * N_DIM + cbase + j * 16] = f2bf(v);
      }
#undef STAGE_A
#undef STAGE_B
#undef RDA
#undef RDB
#undef PHASE_OPEN
#undef PHASE_CLOSE
}

// ---------------- gather: out[m] = w0*y[pos0] + w1*y[pos1] --------------------
__global__ __launch_bounds__(256) void gather_kernel(
    const u16* __restrict__ y, const float* __restrict__ tw,
    const int* __restrict__ pos_of, float* __restrict__ out) {
  int m = blockIdx.x;
  int k = threadIdx.x * 4;
  int p0 = pos_of[m * 2 + 0], p1 = pos_of[m * 2 + 1];
  float w0 = tw[m * 2 + 0], w1 = tw[m * 2 + 1];
  ushort4 y0 = *(const ushort4*)&y[(size_t)p0 * 1024 + k];
  ushort4 y1 = *(const ushort4*)&y[(size_t)p1 * 1024 + k];
  float4 o;
  o.x = w0 * bf2f(y0.x) + w1 * bf2f(y1.x);
  o.y = w0 * bf2f(y0.y) + w1 * bf2f(y1.y);
  o.z = w0 * bf2f(y0.z) + w1 * bf2f(y1.z);
  o.w = w0 * bf2f(y0.w) + w1 * bf2f(y1.w);
  *(float4*)&out[(size_t)m * 1024 + k] = o;
}

extern "C" void kernel_launch(void* const* d_in, const int* in_sizes, int n_in,
                              void* d_out, int out_size, void* d_ws, size_t ws_size,
                              hipStream_t stream) {
  const float* hs = (const float*)d_in[0];
  const float* w1 = (const float*)d_in[1];
  const float* w2 = (const float*)d_in[2];
  const float* tw = (const float*)d_in[3];
  const int* tids = (const int*)d_in[4];
  float* out = (float*)d_out;

  char* ws = (char*)d_ws;
  u16* hsb = (u16*)(ws);                                 //  8 MB  (M,K) bf16
  u16* w1t = (u16*)(ws + (size_t)(8u << 20));            // 32 MB  (E,2N,K) bf16
  u16* w2t = (u16*)(ws + (size_t)(40u << 20));           // 16 MB  (E,K,N)  bf16
  u16* h   = (u16*)(ws + (size_t)(56u << 20));           // 18.9 MB (ROWS_CAP,N)
  u16* y   = (u16*)(ws + (size_t)(76u << 20));           // 18.9 MB (ROWS_CAP,K)
  int* pair_token   = (int*)(ws + (size_t)(96u << 20));
  int* pos_of       = (int*)(ws + (size_t)(96u << 20) + 64 * 1024);
  int* block_expert = (int*)(ws + (size_t)(96u << 20) + 128 * 1024);
  int* blockhist    = (int*)(ws + (size_t)(96u << 20) + 192 * 1024);  // 32*8 ints
  int* baseoff      = (int*)(ws + (size_t)(96u << 20) + 256 * 1024);  // 32*8 ints

  hist_kernel<<<HBLK, 256, 0, stream>>>(tids, blockhist);
  scan_kernel<<<1, 256, 0, stream>>>(blockhist, baseoff, pair_token, block_expert);
  assign_kernel<<<HBLK, 256, 0, stream>>>(tids, baseoff, pair_token, pos_of);
  convert_kernel<<<4096, 256, 0, stream>>>(hs, hsb);
  transpose_convert<<<dim3(16, 32, E_NUM), 256, 0, stream>>>(w1, w1t, 1024, 2048);
  transpose_convert<<<dim3(16, 16, E_NUM), 256, 0, stream>>>(w2, w2t, 1024, 1024);
  // dynamic LDS: NB=2 triple-buffered 144 KB; NB=1 double-buffered 64 KB
  size_t lds1 = (size_t)3 * (128 * 64 + 2 * 128 * 64) * sizeof(u16);  // 147456
  size_t lds2 = (size_t)2 * (128 * 64 + 1 * 128 * 64) * sizeof(u16);  // 65536
  gemm8p<true, 2><<<dim3(NROWBLK, 8), 512, lds1, stream>>>(hsb, w1t, h, pair_token, block_expert);
  gemm8p<false, 1><<<dim3(NROWBLK, 8), 512, lds2, stream>>>(h, w2t, y, pair_token, block_expert);
  gather_kernel<<<4096, 256, 0, stream>>>(y, tw, pos_of, out);
}

// Round 4
// 235.864 us; speedup vs baseline: 1.1190x; 1.1190x over previous
//
#include <hip/hip_runtime.h>

// MoE: M=4096, K=1024, E=8, N=1024, TOPK=2
// out[m] = sum_t topk_w[m,t] * ( silu(hs[m]@w1[e][:, :N]) * (hs[m]@w1[e][:, N:]) ) @ w2[e]

#define M_TOK   4096
#define K_DIM   1024
#define N_DIM   1024
#define E_NUM   8
#define NPAIR   8192            // M_TOK * TOPK
#define BM      128
#define ROWS_CAP 9216           // NPAIR + E_NUM*BM
#define NROWBLK 72              // ROWS_CAP / BM  (divisible by 8 -> bijective XCD swizzle)

typedef unsigned short u16;
typedef unsigned int   u32;
typedef __attribute__((ext_vector_type(8))) short bf16x8;
typedef __attribute__((ext_vector_type(4))) float f32x4;

#define GPTR(p) ((const __attribute__((address_space(1))) u32*)(const void*)(p))
#define LPTR(p) ((__attribute__((address_space(3))) u32*)(void*)(p))

__device__ __forceinline__ u16 f2bf(float f) {
  union { float f; u32 u; } v; v.f = f;
  u32 r = v.u + 0x7FFFu + ((v.u >> 16) & 1u);   // RNE
  return (u16)(r >> 16);
}
__device__ __forceinline__ float bf2f(u16 u) {
  union { u32 u; float f; } v; v.u = ((u32)u) << 16;
  return v.f;
}

// ---------------- fused prep: routing + hs convert + w1/w2 transpose ----------
// One launch replaces 6 (hist/scan/assign/convert/tw1/tw2): saves ~5 dispatch
// overheads (~10us each) and lets the three memory streams fill the GPU
// concurrently instead of serializing three part-idle grids.
// block 0            : routing (single block, deterministic p-order positions)
// blocks 1..4096     : hs fp32 -> bf16 flat convert (float4/lane)
// blocks 4097..8192  : w1 (E,K,2N) f32 -> w1t (E,2N,K) bf16 transpose tiles
// blocks 8193..10240 : w2 (E,N,K)  f32 -> w2t (E,K,N)  bf16 transpose tiles
__device__ __forceinline__ void transpose_tile64(
    const float* __restrict__ src, u16* __restrict__ dst, int R, int Cc,
    int rb, int cb, void* shm) {
  // LDS pad 67: write addr rr*67+c (64 consecutive -> 2-way, free);
  // read addr (4t+j)*67+cc -> bank step 12 -> 2-way max (m136: free).
  float* lds = (float*)shm;                  // [64][67]
  const int r0 = rb * 64, c0 = cb * 64;
  const int t = threadIdx.x;
#pragma unroll
  for (int it = 0; it < 4; ++it) {
    int lin = it * 256 + t;                  // 0..1023
    int rr = lin >> 4, c4 = (lin & 15) << 2;
    float4 v = *(const float4*)&src[(size_t)(r0 + rr) * Cc + c0 + c4];
    lds[rr * 67 + c4 + 0] = v.x; lds[rr * 67 + c4 + 1] = v.y;
    lds[rr * 67 + c4 + 2] = v.z; lds[rr * 67 + c4 + 3] = v.w;
  }
  __syncthreads();
#pragma unroll
  for (int it = 0; it < 4; ++it) {
    int lin = it * 256 + t;
    int cc = lin >> 4, r4 = (lin & 15) << 2;
    ushort4 o;
    o.x = f2bf(lds[(r4 + 0) * 67 + cc]);
    o.y = f2bf(lds[(r4 + 1) * 67 + cc]);
    o.z = f2bf(lds[(r4 + 2) * 67 + cc]);
    o.w = f2bf(lds[(r4 + 3) * 67 + cc]);
    *(ushort4*)&dst[(size_t)(c0 + cc) * R + r0 + r4] = o;
  }
}

__global__ __launch_bounds__(256) void prep_route_kernel(
    const float* __restrict__ hs, const float* __restrict__ w1,
    const float* __restrict__ w2, const int* __restrict__ topk_ids,
    u16* __restrict__ hsb, u16* __restrict__ w1t, u16* __restrict__ w2t,
    int* __restrict__ pair_token, int* __restrict__ pos_of,
    int* __restrict__ block_expert) {
  __shared__ __align__(16) char shm[17408];
  const int bid = blockIdx.x;
  const int t = threadIdx.x;
  if (bid == 0) {
    // ---- routing: hist + scan + assign, fused in one block ----
    int* lcnt = (int*)shm;                   // [256][8] per-thread expert counts
    __shared__ int cnt[E_NUM], off[E_NUM], pad[E_NUM];
    int c[E_NUM];
#pragma unroll
    for (int e = 0; e < E_NUM; ++e) c[e] = 0;
    // thread t owns pairs [t*32, t*32+32) -> deterministic p-order
    for (int i = 0; i < 32; ++i) c[topk_ids[t * 32 + i] & 7]++;
#pragma unroll
    for (int e = 0; e < E_NUM; ++e) lcnt[t * 8 + e] = c[e];
    __syncthreads();
    if (t < E_NUM) {                         // serial exclusive scan per expert
      int run = 0;
      for (int i = 0; i < 256; ++i) {
        int v = lcnt[i * 8 + t]; lcnt[i * 8 + t] = run; run += v;
      }
      cnt[t] = run;
    }
    __syncthreads();
    if (t == 0) {
      int run = 0, blk = 0;
      for (int e = 0; e < E_NUM; ++e) {
        off[e] = run;
        int padded = ((cnt[e] + BM - 1) / BM) * BM;
        pad[e] = padded;
        for (int b = 0; b < padded / BM; ++b) block_expert[blk++] = e;
        run += padded;
      }
      for (; blk < NROWBLK; ++blk) block_expert[blk] = -1;
    }
    __syncthreads();
    // assign: running counter per (thread, expert) in LDS
    for (int i = 0; i < 32; ++i) {
      int p = t * 32 + i;
      int e = topk_ids[p] & 7;
      int idx = t * 8 + e;
      int pos = off[e] + lcnt[idx];
      lcnt[idx] = lcnt[idx] + 1;
      pair_token[pos] = p >> 1;
      pos_of[p] = pos;
    }
    // pad rows point at token 0 (computed, never gathered)
    for (int e = 0; e < E_NUM; ++e) {
      int s = off[e] + cnt[e], epos = off[e] + pad[e];
      for (int r = s + t; r < epos; r += 256) pair_token[r] = 0;
    }
  } else if (bid <= 4096) {
    // ---- hs convert ----
    int i = (bid - 1) * 256 + t;
    float4 v = ((const float4*)hs)[i];
    ushort4 o;
    o.x = f2bf(v.x); o.y = f2bf(v.y); o.z = f2bf(v.z); o.w = f2bf(v.w);
    ((ushort4*)hsb)[i] = o;
  } else if (bid <= 8192) {
    // ---- w1 transpose: R=1024(K), Cc=2048(2N); 512 tiles/expert ----
    int idx = bid - 4097;
    int e = idx >> 9, rem = idx & 511;
    int cb = rem >> 4, rb = rem & 15;
    transpose_tile64(w1 + (size_t)e * 1024 * 2048, w1t + (size_t)e * 1024 * 2048,
                     1024, 2048, rb, cb, shm);
  } else {
    // ---- w2 transpose: R=1024(N), Cc=1024(K); 256 tiles/expert ----
    int idx = bid - 8193;
    int e = idx >> 8, rem = idx & 255;
    int cb = rem >> 4, rb = rem & 15;
    transpose_tile64(w2 + (size_t)e * 1024 * 1024, w2t + (size_t)e * 1024 * 1024,
                     1024, 1024, rb, cb, shm);
  }
}

// ---------------- grouped GEMM, 128x128 tile, NB B-matrices -------------------
// NB=2: fused gate|up GEMM1 -> h = silu(gate)*up.  NB=1: plain GEMM2 -> y.
// Round-2 winner (57.4us GEMM1): 4 waves 2x2, wave 64x64(xNB), acc[NB][4][4],
// single-buffered drain schedule (2ph dbuf and 8ph counted-vmcnt both proven
// non-better in r1/r3 for this shape). Zero-conflict XOR-swizzle staging.
// XCD chunk swizzle (T1): 72 % 8 == 0 -> bx = (b&7)*9 + (b>>3) bijective.
template <bool GATHER, int NB>
__global__ __launch_bounds__(256, NB == 2 ? 2 : 3) void gemm128(
    const u16* __restrict__ A, const u16* __restrict__ Bt, u16* __restrict__ Out,
    const int* __restrict__ pair_token, const int* __restrict__ block_expert) {
  const int bx = ((int)blockIdx.x & 7) * (NROWBLK / 8) + ((int)blockIdx.x >> 3);
  const int e = block_expert[bx];
  if (e < 0) return;
  __shared__ __align__(16) u16 As[128 * 64];
  __shared__ __align__(16) u16 Bs[NB * 128 * 64];
  const int tid = threadIdx.x;
  const int wave = tid >> 6;
  const int lane = tid & 63;
  const int wr = wave >> 1;                  // wave row-group (0..1)
  const int wc = wave & 1;                   // wave col-group (0..1)
  const int srow = wave * 8 + (lane >> 3);   // staging row within 32-row shot
  const int kc = ((lane & 7) ^ (srow & 7)) << 3;  // swizzled src chunk (elems)

  const u16* ap[4];
#pragma unroll
  for (int is = 0; is < 4; ++is) {
    int rt = is * 32 + srow;
    int grow = bx * BM + rt;
    int arow = GATHER ? pair_token[grow] : grow;
    ap[is] = A + (size_t)arow * K_DIM + kc;
  }
  const u16* bp[NB][4];
  const u16* base_e = Bt + (size_t)e * (NB * N_DIM) * K_DIM;
#pragma unroll
  for (int nb = 0; nb < NB; ++nb)
#pragma unroll
    for (int is = 0; is < 4; ++is) {
      int n = nb * N_DIM + blockIdx.y * 128 + is * 32 + srow;
      bp[nb][is] = base_e + (size_t)n * K_DIM + kc;
    }
  u16* alds = As + wave * 512;
  u16* blds = Bs + wave * 512;

  f32x4 acc[NB][4][4];
#pragma unroll
  for (int nb = 0; nb < NB; ++nb)
#pragma unroll
    for (int i = 0; i < 4; ++i)
#pragma unroll
      for (int j = 0; j < 4; ++j) acc[nb][i][j] = f32x4{0.f, 0.f, 0.f, 0.f};

  for (int k0 = 0; k0 < K_DIM; k0 += 64) {
#pragma unroll
    for (int is = 0; is < 4; ++is)
      __builtin_amdgcn_global_load_lds(GPTR(ap[is] + k0), LPTR(alds + is * 2048), 16, 0, 0);
#pragma unroll
    for (int nb = 0; nb < NB; ++nb)
#pragma unroll
      for (int is = 0; is < 4; ++is)
        __builtin_amdgcn_global_load_lds(GPTR(bp[nb][is] + k0), LPTR(blds + nb * 8192 + is * 2048), 16, 0, 0);
    __syncthreads();
#pragma unroll
    for (int ks = 0; ks < 2; ++ks) {
      const int cq = ks * 4 + (lane >> 4);
      bf16x8 af[4], bfr[NB][4];
#pragma unroll
      for (int i = 0; i < 4; ++i) {
        int row = wr * 64 + i * 16 + (lane & 15);
        af[i] = *(const bf16x8*)&As[row * 64 + ((cq ^ (row & 7)) << 3)];
      }
#pragma unroll
      for (int nb = 0; nb < NB; ++nb)
#pragma unroll
        for (int j = 0; j < 4; ++j) {
          int n = wc * 64 + j * 16 + (lane & 15);
          bfr[nb][j] = *(const bf16x8*)&Bs[nb * 8192 + n * 64 + ((cq ^ (n & 7)) << 3)];
        }
#pragma unroll
      for (int nb = 0; nb < NB; ++nb)
#pragma unroll
        for (int i = 0; i < 4; ++i)
#pragma unroll
          for (int j = 0; j < 4; ++j)
            acc[nb][i][j] = __builtin_amdgcn_mfma_f32_16x16x32_bf16(af[i], bfr[nb][j], acc[nb][i][j], 0, 0, 0);
    }
    __syncthreads();
  }

  // epilogue: C/D layout col=lane&15, row=(lane>>4)*4+reg (m89/m91-verified)
  const size_t rbase = (size_t)bx * BM + wr * 64 + ((lane >> 4) * 4);
  const int cbase = blockIdx.y * 128 + wc * 64 + (lane & 15);
#pragma unroll
  for (int i = 0; i < 4; ++i)
#pragma unroll
    for (int j = 0; j < 4; ++j)
#pragma unroll
      for (int r = 0; r < 4; ++r) {
        float v;
        if (NB == 2) {
          float g = acc[0][i][j][r], u = acc[1][i][j][r];
          v = g * u / (1.f + __expf(-g));
        } else {
          v = acc[0][i][j][r];
        }
        Out[(rbase + i * 16 + r) * N_DIM + cbase + j * 16] = f2bf(v);
      }
}

// ---------------- gather: out[m] = w0*y[pos0] + w1*y[pos1] --------------------
__global__ __launch_bounds__(256) void gather_kernel(
    const u16* __restrict__ y, const float* __restrict__ tw,
    const int* __restrict__ pos_of, float* __restrict__ out) {
  int m = blockIdx.x;
  int k = threadIdx.x * 4;
  int p0 = pos_of[m * 2 + 0], p1 = pos_of[m * 2 + 1];
  float w0 = tw[m * 2 + 0], w1 = tw[m * 2 + 1];
  ushort4 y0 = *(const ushort4*)&y[(size_t)p0 * 1024 + k];
  ushort4 y1 = *(const ushort4*)&y[(size_t)p1 * 1024 + k];
  float4 o;
  o.x = w0 * bf2f(y0.x) + w1 * bf2f(y1.x);
  o.y = w0 * bf2f(y0.y) + w1 * bf2f(y1.y);
  o.z = w0 * bf2f(y0.z) + w1 * bf2f(y1.z);
  o.w = w0 * bf2f(y0.w) + w1 * bf2f(y1.w);
  *(float4*)&out[(size_t)m * 1024 + k] = o;
}

extern "C" void kernel_launch(void* const* d_in, const int* in_sizes, int n_in,
                              void* d_out, int out_size, void* d_ws, size_t ws_size,
                              hipStream_t stream) {
  const float* hs = (const float*)d_in[0];
  const float* w1 = (const float*)d_in[1];
  const float* w2 = (const float*)d_in[2];
  const float* tw = (const float*)d_in[3];
  const int* tids = (const int*)d_in[4];
  float* out = (float*)d_out;

  char* ws = (char*)d_ws;
  u16* hsb = (u16*)(ws);                                 //  8 MB  (M,K) bf16
  u16* w1t = (u16*)(ws + (size_t)(8u << 20));            // 32 MB  (E,2N,K) bf16
  u16* w2t = (u16*)(ws + (size_t)(40u << 20));           // 16 MB  (E,K,N)  bf16
  u16* h   = (u16*)(ws + (size_t)(56u << 20));           // 18.9 MB (ROWS_CAP,N)
  u16* y   = (u16*)(ws + (size_t)(76u << 20));           // 18.9 MB (ROWS_CAP,K)
  int* pair_token   = (int*)(ws + (size_t)(96u << 20));
  int* pos_of       = (int*)(ws + (size_t)(96u << 20) + 64 * 1024);
  int* block_expert = (int*)(ws + (size_t)(96u << 20) + 128 * 1024);

  // 4 dispatches total (was 9): prep+route, GEMM1, GEMM2, gather
  prep_route_kernel<<<10241, 256, 0, stream>>>(
      hs, w1, w2, tids, hsb, w1t, w2t, pair_token, pos_of, block_expert);
  gemm128<true, 2><<<dim3(NROWBLK, 8), 256, 0, stream>>>(hsb, w1t, h, pair_token, block_expert);
  gemm128<false, 1><<<dim3(NROWBLK, 8), 256, 0, stream>>>(h, w2t, y, pair_token, block_expert);
  gather_kernel<<<4096, 256, 0, stream>>>(y, tw, pos_of, out);
}